// Round 3
// baseline (217.543 us; speedup 1.0000x reference)
//
#include <hip/hip_runtime.h>
#include <stdint.h>

typedef __bf16 bf16x8 __attribute__((ext_vector_type(8)));
typedef float  f32x4  __attribute__((ext_vector_type(4)));
typedef short  s16x4  __attribute__((ext_vector_type(4)));
typedef unsigned int u32x2 __attribute__((ext_vector_type(2)));
typedef unsigned int u32x4 __attribute__((ext_vector_type(4)));

#define S_   2048
#define DM   1024
// 0.125 (=1/sqrt(64)) * log2(e), folded into Q projection epilogue so the
// attention softmax is a bare exp2 with no per-element scaling.
#define QSCALE 0.18033688011112042f

__device__ __forceinline__ unsigned short f2b(float f) {
    uint32_t u = __builtin_bit_cast(uint32_t, f);
    u += 0x7fffu + ((u >> 16) & 1u);
    return (unsigned short)(u >> 16);
}

// round-half-up bf16 pair pack: 2 adds + 1 v_perm
__device__ __forceinline__ uint32_t pack2bf(float a, float b) {
    uint32_t ua = __builtin_bit_cast(uint32_t, a) + 0x8000u;
    uint32_t ub = __builtin_bit_cast(uint32_t, b) + 0x8000u;
    return __builtin_amdgcn_perm(ub, ua, 0x07060302);
}

__device__ __forceinline__ void glds16(const void* g, void* l) {
    __builtin_amdgcn_global_load_lds(
        (const __attribute__((address_space(1))) void*)g,
        (__attribute__((address_space(3))) void*)l, 16, 0, 0);
}

// ---------------------------------------------------------------------------
// fp32 -> bf16 for X (4M elems -> Xb in ws) and Wq/Wk/Wv (3x1M -> Wb in d_out
// scratch; consumed by qkv_gemm, which finishes before out_gemm writes d_out).
// ---------------------------------------------------------------------------
__global__ void cvt_all(const float* __restrict__ X,
                        const float* __restrict__ Wq, const float* __restrict__ Wk,
                        const float* __restrict__ Wv,
                        unsigned short* __restrict__ Xb, unsigned short* __restrict__ Wb)
{
    size_t i = ((size_t)blockIdx.x * 256 + threadIdx.x) * 4;
    const float* src;
    unsigned short* dst;
    size_t off;
    if (i < (size_t)4194304) { src = X; dst = Xb; off = i; }
    else {
        size_t j = i - 4194304;
        int sel = (int)(j >> 20);
        off = j & 1048575;
        src = (sel == 0) ? Wq : (sel == 1) ? Wk : Wv;
        dst = Wb + (size_t)sel * 1048576;
    }
    float4 v = *(const float4*)&src[off];
    uint2 o;
    o.x = pack2bf(v.x, v.y);
    o.y = pack2bf(v.z, v.w);
    *(uint2*)&dst[off] = o;
}

// Wo fp32 -> bf16 (runs after attn; dest is the dead Qw region)
__global__ void cvt_wo(const float* __restrict__ Wo, unsigned short* __restrict__ Wob)
{
    size_t i = ((size_t)blockIdx.x * 256 + threadIdx.x) * 4;
    float4 v = *(const float4*)&Wo[i];
    uint2 o;
    o.x = pack2bf(v.x, v.y);
    o.y = pack2bf(v.z, v.w);
    *(uint2*)&Wob[i] = o;
}

// ---------------------------------------------------------------------------
// Fused QKV projection, m97 structure: both operands bf16 via global_load_lds.
// z=0: Q[tok][feat] (scaled by QSCALE), z=1: K[tok][feat], z=2: Vt[feat][tok].
// ---------------------------------------------------------------------------
__global__ __launch_bounds__(256, 2)
void qkv_gemm(const unsigned short* __restrict__ Xb,
              const unsigned short* __restrict__ Wqb,
              const unsigned short* __restrict__ Wkb,
              const unsigned short* __restrict__ Wvb,
              unsigned short* __restrict__ Qo, unsigned short* __restrict__ Ko,
              unsigned short* __restrict__ Vto)
{
    __shared__ unsigned short Ash[128 * 32];
    __shared__ unsigned short Bsh[128 * 32];

    const int t = threadIdx.x;
    const int lane = t & 63, w = t >> 6;
    const int lcol = lane & 15, quad = lane >> 4;
    const int z = blockIdx.z;
    const int rowBase = ((z == 2) ? blockIdx.x : blockIdx.y) * 128;
    const int colBase = ((z == 2) ? blockIdx.y : blockIdx.x) * 128;
    const unsigned short* aPtr = (z == 2) ? Wvb : Xb;
    const unsigned short* bPtr = (z == 0) ? Wqb : (z == 1) ? Wkb : Xb;
    const int wr = (w >> 1) * 64, wc = (w & 1) * 64;

    f32x4 acc[4][4];
    #pragma unroll
    for (int i = 0; i < 4; ++i)
        #pragma unroll
        for (int j = 0; j < 4; ++j) acc[i][j] = (f32x4){0.f,0.f,0.f,0.f};

    for (int k0 = 0; k0 < DM; k0 += 32) {
        __syncthreads();
        #pragma unroll
        for (int p = 0; p < 2; ++p) {
            int ci = p * 256 + t;
            glds16(&aPtr[(size_t)(rowBase + (ci >> 2)) * DM + k0 + (ci & 3) * 8], &Ash[ci * 8]);
        }
        #pragma unroll
        for (int p = 0; p < 2; ++p) {
            int ci = p * 256 + t;
            glds16(&bPtr[(size_t)(colBase + (ci >> 2)) * DM + k0 + (ci & 3) * 8], &Bsh[ci * 8]);
        }
        __syncthreads();
        bf16x8 af[4], bfr[4];
        #pragma unroll
        for (int i = 0; i < 4; ++i) af[i]  = *(const bf16x8*)&Ash[(wr + i*16 + lcol)*32 + quad*8];
        #pragma unroll
        for (int i = 0; i < 4; ++i) bfr[i] = *(const bf16x8*)&Bsh[(wc + i*16 + lcol)*32 + quad*8];
        #pragma unroll
        for (int i = 0; i < 4; ++i)
            #pragma unroll
            for (int j = 0; j < 4; ++j)
                acc[i][j] = __builtin_amdgcn_mfma_f32_16x16x32_bf16(af[i], bfr[j], acc[i][j], 0, 0, 0);
    }

    unsigned short* Cm = (z == 0) ? Qo : (z == 1) ? Ko : Vto;
    const int ld = (z == 2) ? (S_ * 2) : DM;
    const float sc = (z == 0) ? QSCALE : 1.0f;
    #pragma unroll
    for (int i = 0; i < 4; ++i)
        #pragma unroll
        for (int j = 0; j < 4; ++j)
            #pragma unroll
            for (int r = 0; r < 4; ++r) {
                int row = rowBase + wr + i*16 + quad*4 + r;
                int col = colBase + wc + j*16 + lcol;
                Cm[(size_t)row * ld + col] = f2b(acc[i][j][r] * sc);
            }
}

// ---------------------------------------------------------------------------
// Flash attention, causal, S^T form, fixed softmax shift.
// R11: latency-bound restructure (R10 counters: MfmaUtil 14%, VALU 31%,
// LDS pipe ~42%, Occupancy 24% -> nothing saturated; per-chunk barrier
// latency dominates with only 2 barrier-domains/CU).
//   * Block = 64 q-rows, 4 waves (2 qg x 2 kh), 256 thr. Grid (32,32) =
//     1024 blocks -> 4 blocks/CU (LDS 4x36.9KB = 147KB): 4 independent
//     barrier-domains per CU fill each other's sync stalls. Per-CU tile set
//     {31-y, 23-y, y, y+8} = 66 chunks, exactly balanced. XCD = x&7 keeps
//     bh->XCD pinning.
//   * PV via v_mfma_f32_16x16x16_bf16: the QK^T C-layout (lane=q,
//     regs=k=quad*4+r) IS the 16x16x16 A-fragment layout, so the packed
//     P words feed PV directly -- shfl_xor exchange + sigma + selects gone
//     (64 ds_swizzles/CU/chunk off the LDS pipe, ~240cyc off the chain).
//     Guarded by __has_builtin; fallback = proven R10 shfl path.
// Causal bounds wave-uniform: k16 idx Kb = c*4 + kh*2 + nk, q16 idx
// Qb = tile*4 + wq*2 + qi, live iff Kb <= Qb, diagonal masked via mk[].
// ---------------------------------------------------------------------------
#if __has_builtin(__builtin_amdgcn_mfma_f32_16x16x16bf16_1k)
#define PV16 1
#else
#define PV16 0
#endif

__global__ __launch_bounds__(256, 4)
void attn_kernel(const unsigned short* __restrict__ Q,
                 const unsigned short* __restrict__ K,
                 const unsigned short* __restrict__ Vt,
                 unsigned short* __restrict__ Z)
{
    // [Kbuf0 | Kbuf1 | Vbuf0 | Vbuf1], each 64 rows x 72 shorts (16B row pad).
    // After the main loop reused as f32 reduction buffer
    // (2 q-groups x 64 lanes x 36 f32 = 18,432B).
    __shared__ __align__(16) unsigned short SH[18432];

    const int t = threadIdx.x;
    const int lane = t & 63, w = t >> 6;          // 4 waves
    const int lcol = lane & 15, quad = lane >> 4;
    const int kh = w & 1, wq = w >> 1;            // k-half (32), q-group (32)

    const int bh = blockIdx.x;                    // XCD = bh & 7
    const int b = bh >> 4, h = bh & 15;
    const int y = blockIdx.y;
    const int tile = (y < 16) ? (31 - y) : (y - 16);
    const int q0 = tile * 64;
    const int nchunk = tile + 1;                  // k-chunks of 64

    const unsigned short* Qg = Q + (size_t)(b * S_ + q0) * DM + h * 64;
    const unsigned short* Kg = K + (size_t)(b * S_) * DM + h * 64;
    const unsigned short* Vg = Vt + (size_t)(h * 64) * (S_ * 2) + b * S_;

    // Q fragments: 2 q-subgroups of 16 x 2 hd-halves
    bf16x8 qf[2][2];
    #pragma unroll
    for (int qi = 0; qi < 2; ++qi)
        #pragma unroll
        for (int kd = 0; kd < 2; ++kd)
            qf[qi][kd] = *(const bf16x8*)&Qg[(size_t)(wq*32 + qi*16 + lcol) * DM + kd*32 + quad*8];

    // mask pattern inside the diagonal 16x16 block (S^T form: mask k > q)
    bool mk[4];
    #pragma unroll
    for (int r = 0; r < 4; ++r) mk[r] = (quad*4 + r) > lcol;

    float lp[2] = {0.f, 0.f};
    f32x4 o[2][4];
    #pragma unroll
    for (int qi = 0; qi < 2; ++qi)
        #pragma unroll
        for (int nd = 0; nd < 4; ++nd) o[qi][nd] = (f32x4){0.f,0.f,0.f,0.f};

    // staging: 64 rows x 8 16B-chunks x {K,V}; 256 thr -> 2 K + 2 V per thread
    const int sr = t >> 3, sch = t & 7;

    // prologue: stage chunk 0 into buffer 0
    #pragma unroll
    for (int p = 0; p < 2; ++p) {
        const int row = p*32 + sr;
        uint4 k0 = *(const uint4*)&Kg[(size_t)row * DM + sch * 8];
        uint4 v0 = *(const uint4*)&Vg[(size_t)row * (S_ * 2) + sch * 8];
        *(uint4*)&SH[row * 72 + sch * 8] = k0;
        *(uint4*)&SH[9216 + row * 72 + sch * 8] = v0;
    }
    __syncthreads();

    const int Qb0 = tile * 4 + wq * 2;                  // q16 idx of qi=0
#if !PV16
    const int gq = ((quad & 1) << 1) | (quad >> 1);     // sigma = [0,2,1,3]
    const bool qodd = (quad & 1) != 0;
#endif

    for (int c = 0; c < nchunk; ++c) {
        const int cur = c & 1;
        const bool pf = (c + 1 < nchunk);
        uint4 kn[2], vn[2];
        if (pf) {                                 // issue loads for chunk c+1
            const int kc1 = (c + 1) * 64;
            #pragma unroll
            for (int p = 0; p < 2; ++p) {
                const int row = p*32 + sr;
                kn[p] = *(const uint4*)&Kg[(size_t)(kc1 + row) * DM + sch * 8];
                vn[p] = *(const uint4*)&Vg[(size_t)row * (S_ * 2) + kc1 + sch * 8];
            }
        }
        const unsigned short* Kc = &SH[cur * 4608];
        const unsigned short* Vc = &SH[9216 + cur * 4608];

        const int Kb0 = c * 4 + kh * 2;           // k16 idx of nk=0
        if (Kb0 <= Qb0 + 1) {                     // at least (nk=0,qi=1) live
            uint32_t pw[2][2][2];                 // [qi][nk][word], bf16 pairs
            #pragma unroll
            for (int nk = 0; nk < 2; ++nk) {
                const int Kb = Kb0 + nk;
                if (Kb <= Qb0 + 1) {
                    bf16x8 ak0 = *(const bf16x8*)&Kc[(kh*32 + nk*16 + lcol)*72 + quad*8];
                    bf16x8 ak1 = *(const bf16x8*)&Kc[(kh*32 + nk*16 + lcol)*72 + 32 + quad*8];
                    #pragma unroll
                    for (int qi = 0; qi < 2; ++qi) {
                        if (Kb <= Qb0 + qi) {
                            f32x4 s = (f32x4){0.f,0.f,0.f,0.f};
                            s = __builtin_amdgcn_mfma_f32_16x16x32_bf16(ak0, qf[qi][0], s, 0, 0, 0);
                            s = __builtin_amdgcn_mfma_f32_16x16x32_bf16(ak1, qf[qi][1], s, 0, 0, 0);
                            float p0 = __builtin_amdgcn_exp2f(s[0]);
                            float p1 = __builtin_amdgcn_exp2f(s[1]);
                            float p2 = __builtin_amdgcn_exp2f(s[2]);
                            float p3 = __builtin_amdgcn_exp2f(s[3]);
                            if (Kb == Qb0 + qi) { // diagonal block, uniform
                                p0 = mk[0] ? 0.f : p0;
                                p1 = mk[1] ? 0.f : p1;
                                p2 = mk[2] ? 0.f : p2;
                                p3 = mk[3] ? 0.f : p3;
                            }
                            lp[qi] += (p0 + p1) + (p2 + p3);
                            pw[qi][nk][0] = pack2bf(p0, p1);
                            pw[qi][nk][1] = pack2bf(p2, p3);
                        } else {
                            pw[qi][nk][0] = 0u;
                            pw[qi][nk][1] = 0u;
                        }
                    }
                } else {
                    #pragma unroll
                    for (int qi = 0; qi < 2; ++qi) {
                        pw[qi][nk][0] = 0u;
                        pw[qi][nk][1] = 0u;
                    }
                }
            }

#if PV16
            // PV: K=16 MFMAs consume the QK C-layout directly.
            // A[row=q=lane&15][k=quad*4+e] == P words pw[qi][nk];
            // B[col=hd=nd*16+lcol][k=quad*4+e] = Vt tokens kh*32+nk*16+quad*4..+3.
            #pragma unroll
            for (int nk = 0; nk < 2; ++nk) {
                if (Kb0 + nk <= Qb0 + 1) {
                    #pragma unroll
                    for (int nd = 0; nd < 4; ++nd) {
                        s16x4 bv = *(const s16x4*)&Vc[(nd*16 + lcol)*72 + kh*32 + nk*16 + quad*4];
                        #pragma unroll
                        for (int qi = 0; qi < 2; ++qi) {
                            u32x2 wv;
                            wv[0] = pw[qi][nk][0];
                            wv[1] = pw[qi][nk][1];
                            s16x4 ap = __builtin_bit_cast(s16x4, wv);
                            o[qi][nd] = __builtin_amdgcn_mfma_f32_16x16x16bf16_1k(
                                            ap, bv, o[qi][nd], 0, 0, 0);
                        }
                    }
                }
            }
#else
            // register->A-fragment transform via shfl_xor(16) + select (R10).
            bf16x8 ap[2];
            #pragma unroll
            for (int qi = 0; qi < 2; ++qi) {
                uint32_t a0 = pw[qi][0][0], a1 = pw[qi][0][1];
                uint32_t b0 = pw[qi][1][0], b1 = pw[qi][1][1];
                uint32_t xa0 = (uint32_t)__shfl_xor((int)a0, 16);
                uint32_t xa1 = (uint32_t)__shfl_xor((int)a1, 16);
                uint32_t xb0 = (uint32_t)__shfl_xor((int)b0, 16);
                uint32_t xb1 = (uint32_t)__shfl_xor((int)b1, 16);
                u32x4 apw;
                apw[0] = qodd ? xb0 : a0;
                apw[1] = qodd ? xb1 : a1;
                apw[2] = qodd ? b0 : xa0;
                apw[3] = qodd ? b1 : xa1;
                ap[qi] = __builtin_bit_cast(bf16x8, apw);
            }
            #pragma unroll
            for (int nd = 0; nd < 4; ++nd) {
                bf16x8 bv = *(const bf16x8*)&Vc[(nd*16 + lcol)*72 + kh*32 + gq*8];
                #pragma unroll
                for (int qi = 0; qi < 2; ++qi)
                    o[qi][nd] = __builtin_amdgcn_mfma_f32_16x16x32_bf16(ap[qi], bv, o[qi][nd], 0, 0, 0);
            }
#endif
        }

        if (pf) {                                 // write chunk c+1 into buf^1
            #pragma unroll
            for (int p = 0; p < 2; ++p) {
                const int row = p*32 + sr;
                *(uint4*)&SH[(cur ^ 1) * 4608 + row * 72 + sch * 8] = kn[p];
                *(uint4*)&SH[9216 + (cur ^ 1) * 4608 + row * 72 + sch * 8] = vn[p];
            }
        }
        __syncthreads();   // readers of buf^1 (iter c-1) done before its write
                           // is visible-required; writers done before iter c+1
    }

    // ---- combine k-halves: partner waves (wq,kh=1) -> (wq,kh=0) via LDS ----
    #pragma unroll
    for (int qi = 0; qi < 2; ++qi) {
        lp[qi] += __shfl_xor(lp[qi], 16);
        lp[qi] += __shfl_xor(lp[qi], 32);
    }
    float* red = (float*)SH;
    float* my = red + (wq * 64 + lane) * 36;      // 144B stride: 16B aligned
    if (kh == 1) {
        #pragma unroll
        for (int qi = 0; qi < 2; ++qi)
            #pragma unroll
            for (int nd = 0; nd < 4; ++nd)
                *(f32x4*)&my[qi*16 + nd*4] = o[qi][nd];
        my[32] = lp[0];
        my[33] = lp[1];
    }
    __syncthreads();
    if (kh == 0) {
        #pragma unroll
        for (int qi = 0; qi < 2; ++qi)
            #pragma unroll
            for (int nd = 0; nd < 4; ++nd)
                o[qi][nd] += *(const f32x4*)&my[qi*16 + nd*4];
        float linv[2];
        linv[0] = 1.0f / (lp[0] + my[32]);
        linv[1] = 1.0f / (lp[1] + my[33]);
        #pragma unroll
        for (int qi = 0; qi < 2; ++qi)
            #pragma unroll
            for (int r = 0; r < 4; ++r) {
                float lr = __shfl(linv[qi], quad*4 + r);
                unsigned short* Zr = Z + (size_t)(b*S_ + q0 + wq*32 + qi*16 + quad*4 + r) * DM + h*64;
                #pragma unroll
                for (int nd = 0; nd < 4; ++nd)
                    Zr[nd*16 + lcol] = f2b(o[qi][nd][r] * lr);
            }
    }
}

// ---------------------------------------------------------------------------
// Output projection: tile 64(M)x128(N), grid (8,64)=512 blocks (2 blocks/CU).
// 256 thr / 4 waves, wave sub-tile 32x64. Both operands bf16 via glds.
// out = Zb @ Wob^T + bo, fp32.
// ---------------------------------------------------------------------------
__global__ __launch_bounds__(256, 4)
void out_gemm(const unsigned short* __restrict__ A,
              const unsigned short* __restrict__ Wob, const float* __restrict__ bo,
              float* __restrict__ Out)
{
    __shared__ unsigned short Ash[64 * 32];
    __shared__ unsigned short Bsh[128 * 32];

    const int t = threadIdx.x;
    const int lane = t & 63, w = t >> 6;          // 4 waves
    const int lcol = lane & 15, quad = lane >> 4;
    const int rowBase = blockIdx.y * 64;
    const int colBase = blockIdx.x * 128;
    const int wr = (w >> 1) * 32, wc = (w & 1) * 64;

    f32x4 acc[2][4];
    #pragma unroll
    for (int i = 0; i < 2; ++i)
        #pragma unroll
        for (int j = 0; j < 4; ++j) acc[i][j] = (f32x4){0.f,0.f,0.f,0.f};

    for (int k0 = 0; k0 < DM; k0 += 32) {
        __syncthreads();
        glds16(&A[(size_t)(rowBase + (t >> 2)) * DM + k0 + (t & 3) * 8], &Ash[t * 8]);
        #pragma unroll
        for (int p = 0; p < 2; ++p) {
            int ci = p * 256 + t;
            glds16(&Wob[(size_t)(colBase + (ci >> 2)) * DM + k0 + (ci & 3) * 8], &Bsh[ci * 8]);
        }
        __syncthreads();
        bf16x8 af[2], bfr[4];
        #pragma unroll
        for (int i = 0; i < 2; ++i) af[i]  = *(const bf16x8*)&Ash[(wr + i*16 + lcol)*32 + quad*8];
        #pragma unroll
        for (int j = 0; j < 4; ++j) bfr[j] = *(const bf16x8*)&Bsh[(wc + j*16 + lcol)*32 + quad*8];
        #pragma unroll
        for (int i = 0; i < 2; ++i)
            #pragma unroll
            for (int j = 0; j < 4; ++j)
                acc[i][j] = __builtin_amdgcn_mfma_f32_16x16x32_bf16(af[i], bfr[j], acc[i][j], 0, 0, 0);
    }

    float bb[4];
    #pragma unroll
    for (int j = 0; j < 4; ++j) bb[j] = bo[colBase + wc + j*16 + lcol];

    #pragma unroll
    for (int i = 0; i < 2; ++i)
        #pragma unroll
        for (int j = 0; j < 4; ++j)
            #pragma unroll
            for (int r = 0; r < 4; ++r) {
                int row = rowBase + wr + i*16 + quad*4 + r;
                int col = colBase + wc + j*16 + lcol;
                Out[(size_t)row * DM + col] = acc[i][j][r] + bb[j];
            }
}

// ---------------------------------------------------------------------------
extern "C" void kernel_launch(void* const* d_in, const int* in_sizes, int n_in,
                              void* d_out, int out_size, void* d_ws, size_t ws_size,
                              hipStream_t stream) {
    const float* X  = (const float*)d_in[0];
    const float* Wq = (const float*)d_in[1];
    const float* Wk = (const float*)d_in[2];
    const float* Wv = (const float*)d_in[3];
    const float* Wo = (const float*)d_in[4];
    const float* bo = (const float*)d_in[5];
    float* out = (float*)d_out;

    // ws (32 MB): [Xb/Zb 8MB][Qw/Wob 8MB][Kw 8MB][Vtw 8MB]
    unsigned short* Xb  = (unsigned short*)d_ws;
    unsigned short* Qw  = Xb + (size_t)4096 * 1024;
    unsigned short* Kw  = Qw + (size_t)4096 * 1024;
    unsigned short* Vtw = Kw + (size_t)4096 * 1024;
    unsigned short* Zb  = Xb;                      // Xb dead after qkv_gemm
    unsigned short* Wob = Qw;                      // Qw dead after attn_kernel
    // bf16 qkv-weights staged in d_out (6 MB of 16 MB); consumed by qkv_gemm,
    // which completes before out_gemm overwrites d_out (stream-ordered).
    unsigned short* Wb  = (unsigned short*)d_out;

    cvt_all<<<dim3(7168), 256, 0, stream>>>(X, Wq, Wk, Wv, Xb, Wb);
    qkv_gemm<<<dim3(8, 32, 3), 256, 0, stream>>>(Xb, Wb, Wb + (size_t)1048576,
                                                 Wb + (size_t)2097152, Qw, Kw, Vtw);
    attn_kernel<<<dim3(32, 32), 256, 0, stream>>>(Qw, Kw, Vtw, Zb);
    cvt_wo<<<dim3(1024), 256, 0, stream>>>(Wo, Wob);
    out_gemm<<<dim3(8, 64), 256, 0, stream>>>(Zb, Wob, bo, out);
}

// Round 5
// 195.856 us; speedup vs baseline: 1.1107x; 1.1107x over previous
//
#include <hip/hip_runtime.h>
#include <stdint.h>

typedef __bf16 bf16x8 __attribute__((ext_vector_type(8)));
typedef float  f32x4  __attribute__((ext_vector_type(4)));
typedef unsigned int u32x4 __attribute__((ext_vector_type(4)));

#define S_   2048
#define DM   1024
// 0.125 (=1/sqrt(64)) * log2(e), folded into Q projection epilogue so the
// attention softmax is a bare exp2 with no per-element scaling.
#define QSCALE 0.18033688011112042f

__device__ __forceinline__ unsigned short f2b(float f) {
    uint32_t u = __builtin_bit_cast(uint32_t, f);
    u += 0x7fffu + ((u >> 16) & 1u);
    return (unsigned short)(u >> 16);
}

// round-half-up bf16 pair pack: 2 adds + 1 v_perm
__device__ __forceinline__ uint32_t pack2bf(float a, float b) {
    uint32_t ua = __builtin_bit_cast(uint32_t, a) + 0x8000u;
    uint32_t ub = __builtin_bit_cast(uint32_t, b) + 0x8000u;
    return __builtin_amdgcn_perm(ub, ua, 0x07060302);
}

__device__ __forceinline__ void glds16(const void* g, void* l) {
    __builtin_amdgcn_global_load_lds(
        (const __attribute__((address_space(1))) void*)g,
        (__attribute__((address_space(3))) void*)l, 16, 0, 0);
}

// ---------------------------------------------------------------------------
// fp32 -> bf16 for X (4M elems -> Xb in ws) and Wq/Wk/Wv (3x1M -> Wb in d_out
// scratch; consumed by qkv_gemm, which finishes before out_gemm writes d_out).
// ---------------------------------------------------------------------------
__global__ void cvt_all(const float* __restrict__ X,
                        const float* __restrict__ Wq, const float* __restrict__ Wk,
                        const float* __restrict__ Wv,
                        unsigned short* __restrict__ Xb, unsigned short* __restrict__ Wb)
{
    size_t i = ((size_t)blockIdx.x * 256 + threadIdx.x) * 4;
    const float* src;
    unsigned short* dst;
    size_t off;
    if (i < (size_t)4194304) { src = X; dst = Xb; off = i; }
    else {
        size_t j = i - 4194304;
        int sel = (int)(j >> 20);
        off = j & 1048575;
        src = (sel == 0) ? Wq : (sel == 1) ? Wk : Wv;
        dst = Wb + (size_t)sel * 1048576;
    }
    float4 v = *(const float4*)&src[off];
    uint2 o;
    o.x = pack2bf(v.x, v.y);
    o.y = pack2bf(v.z, v.w);
    *(uint2*)&dst[off] = o;
}

// Wo fp32 -> bf16 (runs after attn; dest is the dead Qw region)
__global__ void cvt_wo(const float* __restrict__ Wo, unsigned short* __restrict__ Wob)
{
    size_t i = ((size_t)blockIdx.x * 256 + threadIdx.x) * 4;
    float4 v = *(const float4*)&Wo[i];
    uint2 o;
    o.x = pack2bf(v.x, v.y);
    o.y = pack2bf(v.z, v.w);
    *(uint2*)&Wob[i] = o;
}

// ---------------------------------------------------------------------------
// Fused QKV projection, m97 structure: both operands bf16 via global_load_lds.
// z=0: Q[tok][feat] (scaled by QSCALE), z=1: K[tok][feat], z=2: Vt[feat][tok].
// ---------------------------------------------------------------------------
__global__ __launch_bounds__(256, 2)
void qkv_gemm(const unsigned short* __restrict__ Xb,
              const unsigned short* __restrict__ Wqb,
              const unsigned short* __restrict__ Wkb,
              const unsigned short* __restrict__ Wvb,
              unsigned short* __restrict__ Qo, unsigned short* __restrict__ Ko,
              unsigned short* __restrict__ Vto)
{
    __shared__ unsigned short Ash[128 * 32];
    __shared__ unsigned short Bsh[128 * 32];

    const int t = threadIdx.x;
    const int lane = t & 63, w = t >> 6;
    const int lcol = lane & 15, quad = lane >> 4;
    const int z = blockIdx.z;
    const int rowBase = ((z == 2) ? blockIdx.x : blockIdx.y) * 128;
    const int colBase = ((z == 2) ? blockIdx.y : blockIdx.x) * 128;
    const unsigned short* aPtr = (z == 2) ? Wvb : Xb;
    const unsigned short* bPtr = (z == 0) ? Wqb : (z == 1) ? Wkb : Xb;
    const int wr = (w >> 1) * 64, wc = (w & 1) * 64;

    f32x4 acc[4][4];
    #pragma unroll
    for (int i = 0; i < 4; ++i)
        #pragma unroll
        for (int j = 0; j < 4; ++j) acc[i][j] = (f32x4){0.f,0.f,0.f,0.f};

    for (int k0 = 0; k0 < DM; k0 += 32) {
        __syncthreads();
        #pragma unroll
        for (int p = 0; p < 2; ++p) {
            int ci = p * 256 + t;
            glds16(&aPtr[(size_t)(rowBase + (ci >> 2)) * DM + k0 + (ci & 3) * 8], &Ash[ci * 8]);
        }
        #pragma unroll
        for (int p = 0; p < 2; ++p) {
            int ci = p * 256 + t;
            glds16(&bPtr[(size_t)(colBase + (ci >> 2)) * DM + k0 + (ci & 3) * 8], &Bsh[ci * 8]);
        }
        __syncthreads();
        bf16x8 af[4], bfr[4];
        #pragma unroll
        for (int i = 0; i < 4; ++i) af[i]  = *(const bf16x8*)&Ash[(wr + i*16 + lcol)*32 + quad*8];
        #pragma unroll
        for (int i = 0; i < 4; ++i) bfr[i] = *(const bf16x8*)&Bsh[(wc + i*16 + lcol)*32 + quad*8];
        #pragma unroll
        for (int i = 0; i < 4; ++i)
            #pragma unroll
            for (int j = 0; j < 4; ++j)
                acc[i][j] = __builtin_amdgcn_mfma_f32_16x16x32_bf16(af[i], bfr[j], acc[i][j], 0, 0, 0);
    }

    unsigned short* Cm = (z == 0) ? Qo : (z == 1) ? Ko : Vto;
    const int ld = (z == 2) ? (S_ * 2) : DM;
    const float sc = (z == 0) ? QSCALE : 1.0f;
    #pragma unroll
    for (int i = 0; i < 4; ++i)
        #pragma unroll
        for (int j = 0; j < 4; ++j)
            #pragma unroll
            for (int r = 0; r < 4; ++r) {
                int row = rowBase + wr + i*16 + quad*4 + r;
                int col = colBase + wc + j*16 + lcol;
                Cm[(size_t)row * ld + col] = f2b(acc[i][j][r] * sc);
            }
}

// ---------------------------------------------------------------------------
// Flash attention, causal, S^T form, fixed softmax shift.
// R13: fixed-cost amortization. R2 vs R3 proved per-chunk-instance cost is a
// fixed ~3k cycles (3176 @ 8 waves, 3036 @ 4 waves) regardless of contained
// work -> amortize by DOUBLING the chunk to 128 k: instances/CU 34 -> 17.
// Structure: R2-proven 128 q-rows, 512 thr / 8 waves (4 qg x 2 kh), grid
// (32,16) with complementary tile pairing, 2 blocks/CU.
//   * K tile 128x64 (rows 72-pad), V tile 64x128 (rows 136-pad), double-
//     buffered = 70 KB LDS; reduction buffer (36,864B) reuses the same LDS.
//   * P->PV via the R2-PROVEN shfl_xor(16)+select transform (unconditional;
//     R4's device-builtin #if was a host-pass compile trap). Applied per
//     nk-pair {0,1},{2,3} -> 2 K=32 PV MFMAs per nd per qi. pw[] zero-init
//     up front so partially-live pairs are safe.
//   * T5 s_setprio(1) around MFMA clusters.
// Causal: k16 idx Kb = c*8 + kh*4 + nk (nk in 0..3), q16 idx
// Qb = tile*8 + wq*2 + qi, live iff Kb <= Qb, diagonal masked via mk[].
// ---------------------------------------------------------------------------
__global__ __launch_bounds__(512, 4)
void attn_kernel(const unsigned short* __restrict__ Q,
                 const unsigned short* __restrict__ K,
                 const unsigned short* __restrict__ Vt,
                 unsigned short* __restrict__ Z)
{
    // [K0 | K1 | V0 | V1]: K = 128 rows x 72 shorts (18,432B each),
    // V = 64 rows x 136 shorts (17,408B each). Total 71,680B.
    // After the main loop reused as f32 reduction buffer
    // (4 q-groups x 64 lanes x 36 f32 = 36,864B).
    __shared__ __align__(16) unsigned short SH[35840];

    const int t = threadIdx.x;
    const int lane = t & 63, w = t >> 6;          // 8 waves
    const int lcol = lane & 15, quad = lane >> 4;
    const int kh = w & 1, wq = w >> 1;            // k-half (64), q-group (32)

    const int bh = blockIdx.x;                    // XCD = bh & 7
    const int b = bh >> 4, h = bh & 15;
    const int y = blockIdx.y;
    const int tile = (y < 8) ? (15 - y) : (y - 8);
    const int q0 = tile * 128;
    const int nchunk = tile + 1;                  // k-chunks of 128

    const unsigned short* Qg = Q + (size_t)(b * S_ + q0) * DM + h * 64;
    const unsigned short* Kg = K + (size_t)(b * S_) * DM + h * 64;
    const unsigned short* Vg = Vt + (size_t)(h * 64) * (S_ * 2) + b * S_;

    // Q fragments: 2 q-subgroups of 16 x 2 hd-halves
    bf16x8 qf[2][2];
    #pragma unroll
    for (int qi = 0; qi < 2; ++qi)
        #pragma unroll
        for (int kd = 0; kd < 2; ++kd)
            qf[qi][kd] = *(const bf16x8*)&Qg[(size_t)(wq*32 + qi*16 + lcol) * DM + kd*32 + quad*8];

    // mask pattern inside the diagonal 16x16 block (S^T form: mask k > q)
    bool mk[4];
    #pragma unroll
    for (int r = 0; r < 4; ++r) mk[r] = (quad*4 + r) > lcol;

    float lp[2] = {0.f, 0.f};
    f32x4 o[2][4];
    #pragma unroll
    for (int qi = 0; qi < 2; ++qi)
        #pragma unroll
        for (int nd = 0; nd < 4; ++nd) o[qi][nd] = (f32x4){0.f,0.f,0.f,0.f};

    // staging (512 thr): K 128 rows x 8 chunks -> 2/thread; V 64 rows x 16 -> 2/thread
    const int sr = t >> 3, sch = t & 7;           // K: rows sr, 64+sr
    const int vr = t >> 4, vch = t & 15;          // V: rows vr, 32+vr

    // prologue: stage chunk 0 into buffer 0
    {
        uint4 k0a = *(const uint4*)&Kg[(size_t)sr * DM + sch * 8];
        uint4 k0b = *(const uint4*)&Kg[(size_t)(64 + sr) * DM + sch * 8];
        uint4 v0a = *(const uint4*)&Vg[(size_t)vr * (S_ * 2) + vch * 8];
        uint4 v0b = *(const uint4*)&Vg[(size_t)(32 + vr) * (S_ * 2) + vch * 8];
        *(uint4*)&SH[sr * 72 + sch * 8] = k0a;
        *(uint4*)&SH[(64 + sr) * 72 + sch * 8] = k0b;
        *(uint4*)&SH[18432 + vr * 136 + vch * 8] = v0a;
        *(uint4*)&SH[18432 + (32 + vr) * 136 + vch * 8] = v0b;
    }
    __syncthreads();

    const int Qb0 = tile * 8 + wq * 2;                  // q16 idx of qi=0
    const int gq = ((quad & 1) << 1) | (quad >> 1);     // sigma = [0,2,1,3]
    const bool qodd = (quad & 1) != 0;

    for (int c = 0; c < nchunk; ++c) {
        const int cur = c & 1;
        const bool pf = (c + 1 < nchunk);
        uint4 kn[2], vn[2];
        if (pf) {                                 // issue loads for chunk c+1
            const int kc1 = (c + 1) * 128;
            kn[0] = *(const uint4*)&Kg[(size_t)(kc1 + sr) * DM + sch * 8];
            kn[1] = *(const uint4*)&Kg[(size_t)(kc1 + 64 + sr) * DM + sch * 8];
            vn[0] = *(const uint4*)&Vg[(size_t)vr * (S_ * 2) + kc1 + vch * 8];
            vn[1] = *(const uint4*)&Vg[(size_t)(32 + vr) * (S_ * 2) + kc1 + vch * 8];
        }
        const unsigned short* Kc = &SH[cur * 9216];
        const unsigned short* Vc = &SH[18432 + cur * 8704];

        const int Kb0 = c * 8 + kh * 4;           // k16 idx of nk=0
        uint32_t pw[2][4][2];                     // [qi][nk][word], bf16 pairs
        #pragma unroll
        for (int qi = 0; qi < 2; ++qi)
            #pragma unroll
            for (int nk = 0; nk < 4; ++nk) {
                pw[qi][nk][0] = 0u;
                pw[qi][nk][1] = 0u;
            }

        #pragma unroll
        for (int nk = 0; nk < 4; ++nk) {
            const int Kb = Kb0 + nk;
            if (Kb <= Qb0 + 1) {
                bf16x8 ak0 = *(const bf16x8*)&Kc[(kh*64 + nk*16 + lcol)*72 + quad*8];
                bf16x8 ak1 = *(const bf16x8*)&Kc[(kh*64 + nk*16 + lcol)*72 + 32 + quad*8];
                #pragma unroll
                for (int qi = 0; qi < 2; ++qi) {
                    if (Kb <= Qb0 + qi) {
                        f32x4 s = (f32x4){0.f,0.f,0.f,0.f};
                        __builtin_amdgcn_s_setprio(1);
                        s = __builtin_amdgcn_mfma_f32_16x16x32_bf16(ak0, qf[qi][0], s, 0, 0, 0);
                        s = __builtin_amdgcn_mfma_f32_16x16x32_bf16(ak1, qf[qi][1], s, 0, 0, 0);
                        __builtin_amdgcn_s_setprio(0);
                        float p0 = __builtin_amdgcn_exp2f(s[0]);
                        float p1 = __builtin_amdgcn_exp2f(s[1]);
                        float p2 = __builtin_amdgcn_exp2f(s[2]);
                        float p3 = __builtin_amdgcn_exp2f(s[3]);
                        if (Kb == Qb0 + qi) {     // diagonal block, uniform
                            p0 = mk[0] ? 0.f : p0;
                            p1 = mk[1] ? 0.f : p1;
                            p2 = mk[2] ? 0.f : p2;
                            p3 = mk[3] ? 0.f : p3;
                        }
                        lp[qi] += (p0 + p1) + (p2 + p3);
                        pw[qi][nk][0] = pack2bf(p0, p1);
                        pw[qi][nk][1] = pack2bf(p2, p3);
                    }
                }
            }
        }

        // P->A-fragment transform (R2-proven) per nk-pair, then PV (K=32).
        // Source: lane (quad,q) words a0={4q,4q+1} a1={4q+2,4q+3} (nk even),
        //         b0/b1 same for nk odd. Dest quad d holds k-group
        //         sigma(d)*8..+7 ascending, sigma=[0,2,1,3]; V reads apply
        //         the same sigma via gq.
        #pragma unroll
        for (int pr = 0; pr < 2; ++pr) {
            if (Kb0 + 2*pr <= Qb0 + 1) {          // pair live for some qi
                bf16x8 ap[2];
                #pragma unroll
                for (int qi = 0; qi < 2; ++qi) {
                    uint32_t a0 = pw[qi][2*pr][0], a1 = pw[qi][2*pr][1];
                    uint32_t b0 = pw[qi][2*pr+1][0], b1 = pw[qi][2*pr+1][1];
                    uint32_t xa0 = (uint32_t)__shfl_xor((int)a0, 16);
                    uint32_t xa1 = (uint32_t)__shfl_xor((int)a1, 16);
                    uint32_t xb0 = (uint32_t)__shfl_xor((int)b0, 16);
                    uint32_t xb1 = (uint32_t)__shfl_xor((int)b1, 16);
                    u32x4 apw;
                    apw[0] = qodd ? xb0 : a0;
                    apw[1] = qodd ? xb1 : a1;
                    apw[2] = qodd ? b0 : xa0;
                    apw[3] = qodd ? b1 : xa1;
                    ap[qi] = __builtin_bit_cast(bf16x8, apw);
                }
                #pragma unroll
                for (int nd = 0; nd < 4; ++nd) {
                    bf16x8 bv = *(const bf16x8*)&Vc[(nd*16 + lcol)*136 + kh*64 + pr*32 + gq*8];
                    __builtin_amdgcn_s_setprio(1);
                    #pragma unroll
                    for (int qi = 0; qi < 2; ++qi)
                        o[qi][nd] = __builtin_amdgcn_mfma_f32_16x16x32_bf16(ap[qi], bv, o[qi][nd], 0, 0, 0);
                    __builtin_amdgcn_s_setprio(0);
                }
            }
        }

        if (pf) {                                 // write chunk c+1 into buf^1
            *(uint4*)&SH[(cur ^ 1) * 9216 + sr * 72 + sch * 8] = kn[0];
            *(uint4*)&SH[(cur ^ 1) * 9216 + (64 + sr) * 72 + sch * 8] = kn[1];
            *(uint4*)&SH[18432 + (cur ^ 1) * 8704 + vr * 136 + vch * 8] = vn[0];
            *(uint4*)&SH[18432 + (cur ^ 1) * 8704 + (32 + vr) * 136 + vch * 8] = vn[1];
        }
        __syncthreads();   // readers of buf^1 (iter c-1) done before its write
                           // is visible-required; writers done before iter c+1
    }

    // ---- combine k-halves: partner waves (wq,kh=1) -> (wq,kh=0) via LDS ----
    #pragma unroll
    for (int qi = 0; qi < 2; ++qi) {
        lp[qi] += __shfl_xor(lp[qi], 16);
        lp[qi] += __shfl_xor(lp[qi], 32);
    }
    float* red = (float*)SH;
    float* my = red + (wq * 64 + lane) * 36;      // 144B stride: 16B aligned
    if (kh == 1) {
        #pragma unroll
        for (int qi = 0; qi < 2; ++qi)
            #pragma unroll
            for (int nd = 0; nd < 4; ++nd)
                *(f32x4*)&my[qi*16 + nd*4] = o[qi][nd];
        my[32] = lp[0];
        my[33] = lp[1];
    }
    __syncthreads();
    if (kh == 0) {
        #pragma unroll
        for (int qi = 0; qi < 2; ++qi)
            #pragma unroll
            for (int nd = 0; nd < 4; ++nd)
                o[qi][nd] += *(const f32x4*)&my[qi*16 + nd*4];
        float linv[2];
        linv[0] = 1.0f / (lp[0] + my[32]);
        linv[1] = 1.0f / (lp[1] + my[33]);
        #pragma unroll
        for (int qi = 0; qi < 2; ++qi)
            #pragma unroll
            for (int r = 0; r < 4; ++r) {
                float lr = __shfl(linv[qi], quad*4 + r);
                unsigned short* Zr = Z + (size_t)(b*S_ + q0 + wq*32 + qi*16 + quad*4 + r) * DM + h*64;
                #pragma unroll
                for (int nd = 0; nd < 4; ++nd)
                    Zr[nd*16 + lcol] = f2b(o[qi][nd][r] * lr);
            }
    }
}

// ---------------------------------------------------------------------------
// Output projection: tile 64(M)x128(N), grid (8,64)=512 blocks (2 blocks/CU).
// 256 thr / 4 waves, wave sub-tile 32x64. Both operands bf16 via glds.
// out = Zb @ Wob^T + bo, fp32.
// ---------------------------------------------------------------------------
__global__ __launch_bounds__(256, 4)
void out_gemm(const unsigned short* __restrict__ A,
              const unsigned short* __restrict__ Wob, const float* __restrict__ bo,
              float* __restrict__ Out)
{
    __shared__ unsigned short Ash[64 * 32];
    __shared__ unsigned short Bsh[128 * 32];

    const int t = threadIdx.x;
    const int lane = t & 63, w = t >> 6;          // 4 waves
    const int lcol = lane & 15, quad = lane >> 4;
    const int rowBase = blockIdx.y * 64;
    const int colBase = blockIdx.x * 128;
    const int wr = (w >> 1) * 32, wc = (w & 1) * 64;

    f32x4 acc[2][4];
    #pragma unroll
    for (int i = 0; i < 2; ++i)
        #pragma unroll
        for (int j = 0; j < 4; ++j) acc[i][j] = (f32x4){0.f,0.f,0.f,0.f};

    for (int k0 = 0; k0 < DM; k0 += 32) {
        __syncthreads();
        glds16(&A[(size_t)(rowBase + (t >> 2)) * DM + k0 + (t & 3) * 8], &Ash[t * 8]);
        #pragma unroll
        for (int p = 0; p < 2; ++p) {
            int ci = p * 256 + t;
            glds16(&Wob[(size_t)(colBase + (ci >> 2)) * DM + k0 + (ci & 3) * 8], &Bsh[ci * 8]);
        }
        __syncthreads();
        bf16x8 af[2], bfr[4];
        #pragma unroll
        for (int i = 0; i < 2; ++i) af[i]  = *(const bf16x8*)&Ash[(wr + i*16 + lcol)*32 + quad*8];
        #pragma unroll
        for (int j = 0; j < 4; ++j) bfr[j] = *(const bf16x8*)&Bsh[(wc + j*16 + lcol)*32 + quad*8];
        #pragma unroll
        for (int i = 0; i < 2; ++i)
            #pragma unroll
            for (int j = 0; j < 4; ++j)
                acc[i][j] = __builtin_amdgcn_mfma_f32_16x16x32_bf16(af[i], bfr[j], acc[i][j], 0, 0, 0);
    }

    float bb[4];
    #pragma unroll
    for (int j = 0; j < 4; ++j) bb[j] = bo[colBase + wc + j*16 + lcol];

    #pragma unroll
    for (int i = 0; i < 2; ++i)
        #pragma unroll
        for (int j = 0; j < 4; ++j)
            #pragma unroll
            for (int r = 0; r < 4; ++r) {
                int row = rowBase + wr + i*16 + quad*4 + r;
                int col = colBase + wc + j*16 + lcol;
                Out[(size_t)row * DM + col] = acc[i][j][r] + bb[j];
            }
}

// ---------------------------------------------------------------------------
extern "C" void kernel_launch(void* const* d_in, const int* in_sizes, int n_in,
                              void* d_out, int out_size, void* d_ws, size_t ws_size,
                              hipStream_t stream) {
    const float* X  = (const float*)d_in[0];
    const float* Wq = (const float*)d_in[1];
    const float* Wk = (const float*)d_in[2];
    const float* Wv = (const float*)d_in[3];
    const float* Wo = (const float*)d_in[4];
    const float* bo = (const float*)d_in[5];
    float* out = (float*)d_out;

    // ws (32 MB): [Xb/Zb 8MB][Qw/Wob 8MB][Kw 8MB][Vtw 8MB]
    unsigned short* Xb  = (unsigned short*)d_ws;
    unsigned short* Qw  = Xb + (size_t)4096 * 1024;
    unsigned short* Kw  = Qw + (size_t)4096 * 1024;
    unsigned short* Vtw = Kw + (size_t)4096 * 1024;
    unsigned short* Zb  = Xb;                      // Xb dead after qkv_gemm
    unsigned short* Wob = Qw;                      // Qw dead after attn_kernel
    // bf16 qkv-weights staged in d_out (6 MB of 16 MB); consumed by qkv_gemm,
    // which completes before out_gemm overwrites d_out (stream-ordered).
    unsigned short* Wb  = (unsigned short*)d_out;

    cvt_all<<<dim3(7168), 256, 0, stream>>>(X, Wq, Wk, Wv, Xb, Wb);
    qkv_gemm<<<dim3(8, 32, 3), 256, 0, stream>>>(Xb, Wb, Wb + (size_t)1048576,
                                                 Wb + (size_t)2097152, Qw, Kw, Vtw);
    attn_kernel<<<dim3(32, 16), 512, 0, stream>>>(Qw, Kw, Vtw, Zb);
    cvt_wo<<<dim3(1024), 256, 0, stream>>>(Wo, Wob);
    out_gemm<<<dim3(8, 64), 256, 0, stream>>>(Zb, Wob, bo, out);
}

// Round 6
// 185.744 us; speedup vs baseline: 1.1712x; 1.0544x over previous
//
#include <hip/hip_runtime.h>
#include <stdint.h>

typedef __bf16 bf16x8 __attribute__((ext_vector_type(8)));
typedef float  f32x4  __attribute__((ext_vector_type(4)));
typedef unsigned int u32x4 __attribute__((ext_vector_type(4)));

#define S_   2048
#define DM   1024
// 0.125 (=1/sqrt(64)) * log2(e), folded into Q projection epilogue so the
// attention softmax is a bare exp2 with no per-element scaling.
#define QSCALE 0.18033688011112042f

__device__ __forceinline__ unsigned short f2b(float f) {
    uint32_t u = __builtin_bit_cast(uint32_t, f);
    u += 0x7fffu + ((u >> 16) & 1u);
    return (unsigned short)(u >> 16);
}

// round-half-up bf16 pair pack: 2 adds + 1 v_perm
__device__ __forceinline__ uint32_t pack2bf(float a, float b) {
    uint32_t ua = __builtin_bit_cast(uint32_t, a) + 0x8000u;
    uint32_t ub = __builtin_bit_cast(uint32_t, b) + 0x8000u;
    return __builtin_amdgcn_perm(ub, ua, 0x07060302);
}

__device__ __forceinline__ void glds16(const void* g, void* l) {
    __builtin_amdgcn_global_load_lds(
        (const __attribute__((address_space(1))) void*)g,
        (__attribute__((address_space(3))) void*)l, 16, 0, 0);
}

// ---------------------------------------------------------------------------
// fp32 -> bf16 for X (4M elems -> Xb in ws) and Wq/Wk/Wv (3x1M -> Wb in d_out
// scratch; consumed by qkv_gemm, which finishes before out_gemm writes d_out).
// ---------------------------------------------------------------------------
__global__ void cvt_all(const float* __restrict__ X,
                        const float* __restrict__ Wq, const float* __restrict__ Wk,
                        const float* __restrict__ Wv,
                        unsigned short* __restrict__ Xb, unsigned short* __restrict__ Wb)
{
    size_t i = ((size_t)blockIdx.x * 256 + threadIdx.x) * 4;
    const float* src;
    unsigned short* dst;
    size_t off;
    if (i < (size_t)4194304) { src = X; dst = Xb; off = i; }
    else {
        size_t j = i - 4194304;
        int sel = (int)(j >> 20);
        off = j & 1048575;
        src = (sel == 0) ? Wq : (sel == 1) ? Wk : Wv;
        dst = Wb + (size_t)sel * 1048576;
    }
    float4 v = *(const float4*)&src[off];
    uint2 o;
    o.x = pack2bf(v.x, v.y);
    o.y = pack2bf(v.z, v.w);
    *(uint2*)&dst[off] = o;
}

// Wo fp32 -> bf16 (runs after attn; dest is the dead Qw region)
__global__ void cvt_wo(const float* __restrict__ Wo, unsigned short* __restrict__ Wob)
{
    size_t i = ((size_t)blockIdx.x * 256 + threadIdx.x) * 4;
    float4 v = *(const float4*)&Wo[i];
    uint2 o;
    o.x = pack2bf(v.x, v.y);
    o.y = pack2bf(v.z, v.w);
    *(uint2*)&Wob[i] = o;
}

// ---------------------------------------------------------------------------
// Fused QKV projection, m97 structure: both operands bf16 via global_load_lds.
// z=0: Q[tok][feat] (scaled by QSCALE), z=1: K[tok][feat], z=2: Vt[feat][tok].
// ---------------------------------------------------------------------------
__global__ __launch_bounds__(256, 2)
void qkv_gemm(const unsigned short* __restrict__ Xb,
              const unsigned short* __restrict__ Wqb,
              const unsigned short* __restrict__ Wkb,
              const unsigned short* __restrict__ Wvb,
              unsigned short* __restrict__ Qo, unsigned short* __restrict__ Ko,
              unsigned short* __restrict__ Vto)
{
    __shared__ unsigned short Ash[128 * 32];
    __shared__ unsigned short Bsh[128 * 32];

    const int t = threadIdx.x;
    const int lane = t & 63, w = t >> 6;
    const int lcol = lane & 15, quad = lane >> 4;
    const int z = blockIdx.z;
    const int rowBase = ((z == 2) ? blockIdx.x : blockIdx.y) * 128;
    const int colBase = ((z == 2) ? blockIdx.y : blockIdx.x) * 128;
    const unsigned short* aPtr = (z == 2) ? Wvb : Xb;
    const unsigned short* bPtr = (z == 0) ? Wqb : (z == 1) ? Wkb : Xb;
    const int wr = (w >> 1) * 64, wc = (w & 1) * 64;

    f32x4 acc[4][4];
    #pragma unroll
    for (int i = 0; i < 4; ++i)
        #pragma unroll
        for (int j = 0; j < 4; ++j) acc[i][j] = (f32x4){0.f,0.f,0.f,0.f};

    for (int k0 = 0; k0 < DM; k0 += 32) {
        __syncthreads();
        #pragma unroll
        for (int p = 0; p < 2; ++p) {
            int ci = p * 256 + t;
            glds16(&aPtr[(size_t)(rowBase + (ci >> 2)) * DM + k0 + (ci & 3) * 8], &Ash[ci * 8]);
        }
        #pragma unroll
        for (int p = 0; p < 2; ++p) {
            int ci = p * 256 + t;
            glds16(&bPtr[(size_t)(colBase + (ci >> 2)) * DM + k0 + (ci & 3) * 8], &Bsh[ci * 8]);
        }
        __syncthreads();
        bf16x8 af[4], bfr[4];
        #pragma unroll
        for (int i = 0; i < 4; ++i) af[i]  = *(const bf16x8*)&Ash[(wr + i*16 + lcol)*32 + quad*8];
        #pragma unroll
        for (int i = 0; i < 4; ++i) bfr[i] = *(const bf16x8*)&Bsh[(wc + i*16 + lcol)*32 + quad*8];
        #pragma unroll
        for (int i = 0; i < 4; ++i)
            #pragma unroll
            for (int j = 0; j < 4; ++j)
                acc[i][j] = __builtin_amdgcn_mfma_f32_16x16x32_bf16(af[i], bfr[j], acc[i][j], 0, 0, 0);
    }

    unsigned short* Cm = (z == 0) ? Qo : (z == 1) ? Ko : Vto;
    const int ld = (z == 2) ? (S_ * 2) : DM;
    const float sc = (z == 0) ? QSCALE : 1.0f;
    #pragma unroll
    for (int i = 0; i < 4; ++i)
        #pragma unroll
        for (int j = 0; j < 4; ++j)
            #pragma unroll
            for (int r = 0; r < 4; ++r) {
                int row = rowBase + wr + i*16 + quad*4 + r;
                int col = colBase + wc + j*16 + lcol;
                Cm[(size_t)row * ld + col] = f2b(acc[i][j][r] * sc);
            }
}

// ---------------------------------------------------------------------------
// Flash attention, causal, S^T form, fixed softmax shift.
// R14: balanced split-k. Model (validated on R2: 32 chunks x 3.4k cyc = 108k
// = measured): dispatch = straggler block's SERIAL chunk chain. R2's pairing
// left one 32-chunk straggler; R5's bigger chunks regressed (L grew).
// Fix: every block gets EXACTLY 17 chunks of the R2-proven structure.
//   grid (32 bh, 16): y<8 -> block A (p=y): tile H=15-p, chunks [0,17).
//   y>=8 -> block B (p=y-8): tile H chunks [17, 2H+2), then tile L=p
//   chunks [0, 2p+2). 17 chunks each; A_p/B_p co-resident per CU.
// Fixed-shift softmax => partials combine LINEARLY: A and B write partial
// o (f32, d_out scratch: A at [0,8MB), B at [8,16MB)) and stash l in the
// (unwritten) heavy Z-tile rows 0..3 (A) / 4..7 (B); attn_combine merges.
// Light tiles are finalized in-block by B. Inner loop = R2 byte-for-byte.
// ---------------------------------------------------------------------------
__global__ __launch_bounds__(512, 4)
void attn_kernel(const unsigned short* __restrict__ Q,
                 const unsigned short* __restrict__ K,
                 const unsigned short* __restrict__ Vt,
                 unsigned short* __restrict__ Z,
                 float* __restrict__ Part)
{
    // [Kbuf0 | Kbuf1 | Vbuf0 | Vbuf1], each 64 rows x 72 shorts (16B row pad).
    // Reused per-seg as the f32 reduction buffer (256 lanes x 36 f32).
    __shared__ __align__(16) unsigned short SH[18432];

    const int t = threadIdx.x;
    const int lane = t & 63, w = t >> 6;          // 8 waves
    const int lcol = lane & 15, quad = lane >> 4;
    const int kh = w & 1, wq = w >> 1;            // k-half (32), q-group (32)

    const int bh = blockIdx.x;                    // XCD = bh & 7
    const int b = bh >> 4, h = bh & 15;
    const int y = blockIdx.y;
    const int ab = y >> 3;                        // 0 = A, 1 = B
    const int p = y & 7;
    const int Hv = 15 - p;                        // heavy tile
    const int nH = 2 * Hv + 2;

    const unsigned short* Kg = K + (size_t)(b * S_) * DM + h * 64;
    const unsigned short* Vg = Vt + (size_t)(h * 64) * (S_ * 2) + b * S_;

    // mask pattern inside the diagonal 16x16 block (S^T form: mask k > q)
    bool mk[4];
    #pragma unroll
    for (int r = 0; r < 4; ++r) mk[r] = (quad*4 + r) > lcol;

    // staging: 64 rows x 8 16B-chunks per tile; one K + one V load per thread
    const int sr = t >> 3, sch = t & 7;

    const int gq = ((quad & 1) << 1) | (quad >> 1);     // sigma = [0,2,1,3]
    const bool qodd = (quad & 1) != 0;

    const int nseg = (ab == 0) ? 1 : 2;
    for (int seg = 0; seg < nseg; ++seg) {
        int tile, c0, c1;
        bool finalSeg;
        if (ab == 0)      { tile = Hv; c0 = 0;  c1 = 17;      finalSeg = false; }
        else if (seg == 0){ tile = Hv; c0 = 17; c1 = nH;      finalSeg = false; }
        else              { tile = p;  c0 = 0;  c1 = 2*p + 2; finalSeg = true;  }

        const int q0 = tile * 128;
        const unsigned short* Qg = Q + (size_t)(b * S_ + q0) * DM + h * 64;

        // Q fragments: 2 q-subgroups of 16 x 2 hd-halves
        bf16x8 qf[2][2];
        #pragma unroll
        for (int qi = 0; qi < 2; ++qi)
            #pragma unroll
            for (int kd = 0; kd < 2; ++kd)
                qf[qi][kd] = *(const bf16x8*)&Qg[(size_t)(wq*32 + qi*16 + lcol) * DM + kd*32 + quad*8];

        float lp[2] = {0.f, 0.f};
        f32x4 o[2][4];
        #pragma unroll
        for (int qi = 0; qi < 2; ++qi)
            #pragma unroll
            for (int nd = 0; nd < 4; ++nd) o[qi][nd] = (f32x4){0.f,0.f,0.f,0.f};

        // prologue: stage chunk c0 into buffer c0&1
        {
            const int kc0 = c0 * 64;
            uint4 k0 = *(const uint4*)&Kg[(size_t)(kc0 + sr) * DM + sch * 8];
            uint4 v0 = *(const uint4*)&Vg[(size_t)sr * (S_ * 2) + kc0 + sch * 8];
            *(uint4*)&SH[(c0 & 1) * 4608 + sr * 72 + sch * 8] = k0;
            *(uint4*)&SH[9216 + (c0 & 1) * 4608 + sr * 72 + sch * 8] = v0;
        }
        __syncthreads();

        const int Qb0 = tile * 8 + wq * 2;        // q16 idx of qi=0

        for (int c = c0; c < c1; ++c) {
            const int cur = c & 1;
            const bool pf = (c + 1 < c1);
            uint4 kn, vn;
            if (pf) {                             // issue loads for chunk c+1
                const int kc1 = (c + 1) * 64;
                kn = *(const uint4*)&Kg[(size_t)(kc1 + sr) * DM + sch * 8];
                vn = *(const uint4*)&Vg[(size_t)sr * (S_ * 2) + kc1 + sch * 8];
            }
            const unsigned short* Kc = &SH[cur * 4608];
            const unsigned short* Vc = &SH[9216 + cur * 4608];

            const int Kb0 = c * 4 + kh * 2;       // k16 idx of nk=0
            if (Kb0 <= Qb0 + 1) {                 // at least (nk=0,qi=1) live
                uint32_t pw[2][2][2];             // [qi][nk][word], bf16 pairs
                #pragma unroll
                for (int nk = 0; nk < 2; ++nk) {
                    const int Kb = Kb0 + nk;
                    if (Kb <= Qb0 + 1) {
                        bf16x8 ak0 = *(const bf16x8*)&Kc[(kh*32 + nk*16 + lcol)*72 + quad*8];
                        bf16x8 ak1 = *(const bf16x8*)&Kc[(kh*32 + nk*16 + lcol)*72 + 32 + quad*8];
                        #pragma unroll
                        for (int qi = 0; qi < 2; ++qi) {
                            if (Kb <= Qb0 + qi) {
                                f32x4 s = (f32x4){0.f,0.f,0.f,0.f};
                                s = __builtin_amdgcn_mfma_f32_16x16x32_bf16(ak0, qf[qi][0], s, 0, 0, 0);
                                s = __builtin_amdgcn_mfma_f32_16x16x32_bf16(ak1, qf[qi][1], s, 0, 0, 0);
                                float p0 = __builtin_amdgcn_exp2f(s[0]);
                                float p1 = __builtin_amdgcn_exp2f(s[1]);
                                float p2 = __builtin_amdgcn_exp2f(s[2]);
                                float p3 = __builtin_amdgcn_exp2f(s[3]);
                                if (Kb == Qb0 + qi) { // diagonal block, uniform
                                    p0 = mk[0] ? 0.f : p0;
                                    p1 = mk[1] ? 0.f : p1;
                                    p2 = mk[2] ? 0.f : p2;
                                    p3 = mk[3] ? 0.f : p3;
                                }
                                lp[qi] += (p0 + p1) + (p2 + p3);
                                pw[qi][nk][0] = pack2bf(p0, p1);
                                pw[qi][nk][1] = pack2bf(p2, p3);
                            } else {
                                pw[qi][nk][0] = 0u;
                                pw[qi][nk][1] = 0u;
                            }
                        }
                    } else {
                        #pragma unroll
                        for (int qi = 0; qi < 2; ++qi) {
                            pw[qi][nk][0] = 0u;
                            pw[qi][nk][1] = 0u;
                        }
                    }
                }

                // register->A-fragment transform via shfl_xor(16) + select.
                bf16x8 ap[2];
                #pragma unroll
                for (int qi = 0; qi < 2; ++qi) {
                    uint32_t a0 = pw[qi][0][0], a1 = pw[qi][0][1];
                    uint32_t b0 = pw[qi][1][0], b1 = pw[qi][1][1];
                    uint32_t xa0 = (uint32_t)__shfl_xor((int)a0, 16);
                    uint32_t xa1 = (uint32_t)__shfl_xor((int)a1, 16);
                    uint32_t xb0 = (uint32_t)__shfl_xor((int)b0, 16);
                    uint32_t xb1 = (uint32_t)__shfl_xor((int)b1, 16);
                    u32x4 apw;
                    apw[0] = qodd ? xb0 : a0;
                    apw[1] = qodd ? xb1 : a1;
                    apw[2] = qodd ? b0 : xa0;
                    apw[3] = qodd ? b1 : xa1;
                    ap[qi] = __builtin_bit_cast(bf16x8, apw);
                }

                #pragma unroll
                for (int nd = 0; nd < 4; ++nd) {
                    bf16x8 bv = *(const bf16x8*)&Vc[(nd*16 + lcol)*72 + kh*32 + gq*8];
                    #pragma unroll
                    for (int qi = 0; qi < 2; ++qi)
                        o[qi][nd] = __builtin_amdgcn_mfma_f32_16x16x32_bf16(ap[qi], bv, o[qi][nd], 0, 0, 0);
                }
            }

            if (pf) {                             // write chunk c+1 into buf^1
                *(uint4*)&SH[(cur ^ 1) * 4608 + sr * 72 + sch * 8] = kn;
                *(uint4*)&SH[9216 + (cur ^ 1) * 4608 + sr * 72 + sch * 8] = vn;
            }
            __syncthreads();
        }

        // ---- combine k-halves: (wq,kh=1) -> (wq,kh=0) via LDS ----
        #pragma unroll
        for (int qi = 0; qi < 2; ++qi) {
            lp[qi] += __shfl_xor(lp[qi], 16);
            lp[qi] += __shfl_xor(lp[qi], 32);
        }
        float* red = (float*)SH;
        float* my = red + (wq * 64 + lane) * 36;  // 144B stride: 16B aligned
        if (kh == 1) {
            #pragma unroll
            for (int qi = 0; qi < 2; ++qi)
                #pragma unroll
                for (int nd = 0; nd < 4; ++nd)
                    *(f32x4*)&my[qi*16 + nd*4] = o[qi][nd];
            my[32] = lp[0];
            my[33] = lp[1];
        }
        __syncthreads();
        if (kh == 0) {
            #pragma unroll
            for (int qi = 0; qi < 2; ++qi)
                #pragma unroll
                for (int nd = 0; nd < 4; ++nd)
                    o[qi][nd] += *(const f32x4*)&my[qi*16 + nd*4];
            float ltot[2];
            ltot[0] = lp[0] + my[32];
            ltot[1] = lp[1] + my[33];

            if (finalSeg) {
                float linv[2];
                linv[0] = 1.0f / ltot[0];
                linv[1] = 1.0f / ltot[1];
                #pragma unroll
                for (int qi = 0; qi < 2; ++qi)
                    #pragma unroll
                    for (int r = 0; r < 4; ++r) {
                        float lr = __shfl(linv[qi], quad*4 + r);
                        unsigned short* Zr = Z + (size_t)(b*S_ + q0 + wq*32 + qi*16 + quad*4 + r) * DM + h*64;
                        #pragma unroll
                        for (int nd = 0; nd < 4; ++nd)
                            Zr[nd*16 + lcol] = f2b(o[qi][nd][r] * lr);
                    }
            } else {
                // partial o -> scratch slot; l -> Z-tile stash rows (A:0..3, B:4..7)
                float* po = Part + (size_t)(ab ? 2097152 : 0) + (size_t)(bh*8 + p) * 8192;
                #pragma unroll
                for (int qi = 0; qi < 2; ++qi)
                    #pragma unroll
                    for (int nd = 0; nd < 4; ++nd)
                        #pragma unroll
                        for (int r = 0; r < 4; ++r)
                            po[(wq*32 + qi*16 + quad*4 + r)*64 + nd*16 + lcol] = o[qi][nd][r];
                if (quad == 0) {
                    float* st = (float*)(Z + (size_t)(b*S_ + Hv*128 + wq + (ab ? 4 : 0)) * DM + h*64);
                    st[lcol]      = ltot[0];
                    st[16 + lcol] = ltot[1];
                }
            }
        }
        __syncthreads();   // my[] reads done before next seg's staging writes
    }
}

// ---------------------------------------------------------------------------
// Merge heavy-tile partials: Z = (oA + oB) / (lA + lB). grid(256) x 256 thr;
// block -> (bh, p), heavy tile H = 15-p. l stashed in Z-tile rows 0..7.
// ---------------------------------------------------------------------------
__global__ __launch_bounds__(256)
void attn_combine(const float* __restrict__ Part, unsigned short* __restrict__ Z)
{
    const int blk = blockIdx.x;
    const int bh = blk >> 3, p = blk & 7;
    const int b = bh >> 4, h = bh & 15;
    const int Hv = 15 - p;
    const int t = threadIdx.x;
    const int row = t >> 1, ch = (t & 1) * 32;

    const float* pa = Part + (size_t)blk * 8192;
    const float* pb = Part + 2097152 + (size_t)blk * 8192;

    const float* stA = (const float*)(Z + (size_t)(b*S_ + Hv*128 + (row >> 5)) * DM + h*64);
    const float* stB = (const float*)(Z + (size_t)(b*S_ + Hv*128 + 4 + (row >> 5)) * DM + h*64);
    float lA = stA[row & 31];
    float lB = stB[row & 31];
    __syncthreads();
    float linv = 1.0f / (lA + lB);

    unsigned short* Zr = Z + (size_t)(b*S_ + Hv*128 + row) * DM + h*64;
    #pragma unroll
    for (int j = 0; j < 8; ++j) {
        f32x4 va = *(const f32x4*)&pa[row*64 + ch + j*4];
        f32x4 vb = *(const f32x4*)&pb[row*64 + ch + j*4];
        uint2 ozz;
        float v0 = (va[0] + vb[0]) * linv;
        float v1 = (va[1] + vb[1]) * linv;
        float v2 = (va[2] + vb[2]) * linv;
        float v3 = (va[3] + vb[3]) * linv;
        ozz.x = pack2bf(v0, v1);
        ozz.y = pack2bf(v2, v3);
        *(uint2*)&Zr[ch + j*4] = ozz;
    }
}

// ---------------------------------------------------------------------------
// Output projection: tile 64(M)x128(N), grid (8,64)=512 blocks (2 blocks/CU).
// 256 thr / 4 waves, wave sub-tile 32x64. Both operands bf16 via glds.
// out = Zb @ Wob^T + bo, fp32.
// ---------------------------------------------------------------------------
__global__ __launch_bounds__(256, 4)
void out_gemm(const unsigned short* __restrict__ A,
              const unsigned short* __restrict__ Wob, const float* __restrict__ bo,
              float* __restrict__ Out)
{
    __shared__ unsigned short Ash[64 * 32];
    __shared__ unsigned short Bsh[128 * 32];

    const int t = threadIdx.x;
    const int lane = t & 63, w = t >> 6;          // 4 waves
    const int lcol = lane & 15, quad = lane >> 4;
    const int rowBase = blockIdx.y * 64;
    const int colBase = blockIdx.x * 128;
    const int wr = (w >> 1) * 32, wc = (w & 1) * 64;

    f32x4 acc[2][4];
    #pragma unroll
    for (int i = 0; i < 2; ++i)
        #pragma unroll
        for (int j = 0; j < 4; ++j) acc[i][j] = (f32x4){0.f,0.f,0.f,0.f};

    for (int k0 = 0; k0 < DM; k0 += 32) {
        __syncthreads();
        glds16(&A[(size_t)(rowBase + (t >> 2)) * DM + k0 + (t & 3) * 8], &Ash[t * 8]);
        #pragma unroll
        for (int p = 0; p < 2; ++p) {
            int ci = p * 256 + t;
            glds16(&Wob[(size_t)(colBase + (ci >> 2)) * DM + k0 + (ci & 3) * 8], &Bsh[ci * 8]);
        }
        __syncthreads();
        bf16x8 af[2], bfr[4];
        #pragma unroll
        for (int i = 0; i < 2; ++i) af[i]  = *(const bf16x8*)&Ash[(wr + i*16 + lcol)*32 + quad*8];
        #pragma unroll
        for (int j = 0; j < 4; ++j) bfr[j] = *(const bf16x8*)&Bsh[(wc + j*16 + lcol)*32 + quad*8];
        #pragma unroll
        for (int i = 0; i < 2; ++i)
            #pragma unroll
            for (int j = 0; j < 4; ++j)
                acc[i][j] = __builtin_amdgcn_mfma_f32_16x16x32_bf16(af[i], bfr[j], acc[i][j], 0, 0, 0);
    }

    float bb[4];
    #pragma unroll
    for (int j = 0; j < 4; ++j) bb[j] = bo[colBase + wc + j*16 + lcol];

    #pragma unroll
    for (int i = 0; i < 2; ++i)
        #pragma unroll
        for (int j = 0; j < 4; ++j)
            #pragma unroll
            for (int r = 0; r < 4; ++r) {
                int row = rowBase + wr + i*16 + quad*4 + r;
                int col = colBase + wc + j*16 + lcol;
                Out[(size_t)row * DM + col] = acc[i][j][r] + bb[j];
            }
}

// ---------------------------------------------------------------------------
extern "C" void kernel_launch(void* const* d_in, const int* in_sizes, int n_in,
                              void* d_out, int out_size, void* d_ws, size_t ws_size,
                              hipStream_t stream) {
    const float* X  = (const float*)d_in[0];
    const float* Wq = (const float*)d_in[1];
    const float* Wk = (const float*)d_in[2];
    const float* Wv = (const float*)d_in[3];
    const float* Wo = (const float*)d_in[4];
    const float* bo = (const float*)d_in[5];
    float* out = (float*)d_out;

    // ws (32 MB): [Xb/Zb 8MB][Qw/Wob 8MB][Kw 8MB][Vtw 8MB]
    unsigned short* Xb  = (unsigned short*)d_ws;
    unsigned short* Qw  = Xb + (size_t)4096 * 1024;
    unsigned short* Kw  = Qw + (size_t)4096 * 1024;
    unsigned short* Vtw = Kw + (size_t)4096 * 1024;
    unsigned short* Zb  = Xb;                      // Xb dead after qkv_gemm
    unsigned short* Wob = Qw;                      // Qw dead after attn_kernel
    // d_out (16 MB) triple-duty scratch: bf16 qkv-weights (6 MB) consumed by
    // qkv_gemm; then f32 attn partials (A at [0,8MB), B at [8,16MB)) consumed
    // by attn_combine; then overwritten by out_gemm (stream-ordered).
    unsigned short* Wb  = (unsigned short*)d_out;

    cvt_all<<<dim3(7168), 256, 0, stream>>>(X, Wq, Wk, Wv, Xb, Wb);
    qkv_gemm<<<dim3(8, 32, 3), 256, 0, stream>>>(Xb, Wb, Wb + (size_t)1048576,
                                                 Wb + (size_t)2097152, Qw, Kw, Vtw);
    attn_kernel<<<dim3(32, 16), 512, 0, stream>>>(Qw, Kw, Vtw, Zb, (float*)d_out);
    attn_combine<<<dim3(256), 256, 0, stream>>>((const float*)d_out, Zb);
    cvt_wo<<<dim3(1024), 256, 0, stream>>>(Wo, Wob);
    out_gemm<<<dim3(8, 64), 256, 0, stream>>>(Zb, Wob, bo, out);
}

// Round 9
// 179.619 us; speedup vs baseline: 1.2111x; 1.0341x over previous
//
#include <hip/hip_runtime.h>
#include <stdint.h>

typedef __bf16 bf16x8 __attribute__((ext_vector_type(8)));
typedef float  f32x4  __attribute__((ext_vector_type(4)));
typedef unsigned int u32x4 __attribute__((ext_vector_type(4)));

#define S_   2048
#define DM   1024
// 0.125 (=1/sqrt(64)) * log2(e), folded into Q projection epilogue so the
// attention softmax is a bare exp2 with no per-element scaling.
#define QSCALE 0.18033688011112042f

__device__ __forceinline__ unsigned short f2b(float f) {
    uint32_t u = __builtin_bit_cast(uint32_t, f);
    u += 0x7fffu + ((u >> 16) & 1u);
    return (unsigned short)(u >> 16);
}

// round-half-up bf16 pair pack: 2 adds + 1 v_perm
__device__ __forceinline__ uint32_t pack2bf(float a, float b) {
    uint32_t ua = __builtin_bit_cast(uint32_t, a) + 0x8000u;
    uint32_t ub = __builtin_bit_cast(uint32_t, b) + 0x8000u;
    return __builtin_amdgcn_perm(ub, ua, 0x07060302);
}

__device__ __forceinline__ void glds16(const void* g, void* l) {
    __builtin_amdgcn_global_load_lds(
        (const __attribute__((address_space(1))) void*)g,
        (__attribute__((address_space(3))) void*)l, 16, 0, 0);
}

// ---------------------------------------------------------------------------
// fp32 -> bf16 for X (4M elems -> Xb in ws) and Wq/Wk/Wv (3x1M -> Wb in d_out
// scratch; consumed by qkv_gemm, which finishes before out_gemm writes d_out).
// ---------------------------------------------------------------------------
__global__ void cvt_all(const float* __restrict__ X,
                        const float* __restrict__ Wq, const float* __restrict__ Wk,
                        const float* __restrict__ Wv,
                        unsigned short* __restrict__ Xb, unsigned short* __restrict__ Wb)
{
    size_t i = ((size_t)blockIdx.x * 256 + threadIdx.x) * 4;
    const float* src;
    unsigned short* dst;
    size_t off;
    if (i < (size_t)4194304) { src = X; dst = Xb; off = i; }
    else {
        size_t j = i - 4194304;
        int sel = (int)(j >> 20);
        off = j & 1048575;
        src = (sel == 0) ? Wq : (sel == 1) ? Wk : Wv;
        dst = Wb + (size_t)sel * 1048576;
    }
    float4 v = *(const float4*)&src[off];
    uint2 o;
    o.x = pack2bf(v.x, v.y);
    o.y = pack2bf(v.z, v.w);
    *(uint2*)&dst[off] = o;
}

// Wo fp32 -> bf16 (runs after attn; dest is the dead Qw region)
__global__ void cvt_wo(const float* __restrict__ Wo, unsigned short* __restrict__ Wob)
{
    size_t i = ((size_t)blockIdx.x * 256 + threadIdx.x) * 4;
    float4 v = *(const float4*)&Wo[i];
    uint2 o;
    o.x = pack2bf(v.x, v.y);
    o.y = pack2bf(v.z, v.w);
    *(uint2*)&Wob[i] = o;
}

// ---------------------------------------------------------------------------
// Fused QKV projection, m97 structure: both operands bf16 via global_load_lds.
// z=0: Q[tok][feat] (scaled by QSCALE), z=1: K[tok][feat], z=2: Vt[feat][tok].
// R15: grid (32,8,3); the 32-range (token panels for z!=2) rides blockIdx.x,
// so XCD = x&7 and the 4 same-x-mod-8 token panels stay in one XCD's L2 (X
// read ~once device-wide; only the 2MB weight panels are fetched per-XCD).
// ---------------------------------------------------------------------------
__global__ __launch_bounds__(256, 2)
void qkv_gemm(const unsigned short* __restrict__ Xb,
              const unsigned short* __restrict__ Wqb,
              const unsigned short* __restrict__ Wkb,
              const unsigned short* __restrict__ Wvb,
              unsigned short* __restrict__ Qo, unsigned short* __restrict__ Ko,
              unsigned short* __restrict__ Vto)
{
    __shared__ unsigned short Ash[128 * 32];
    __shared__ unsigned short Bsh[128 * 32];

    const int t = threadIdx.x;
    const int lane = t & 63, w = t >> 6;
    const int lcol = lane & 15, quad = lane >> 4;
    const int z = blockIdx.z;
    // x spans 32 (token panels), y spans 8 (feature panels); roles swap at z=2
    const int rowBase = ((z == 2) ? blockIdx.y : blockIdx.x) * 128;
    const int colBase = ((z == 2) ? blockIdx.x : blockIdx.y) * 128;
    const unsigned short* aPtr = (z == 2) ? Wvb : Xb;
    const unsigned short* bPtr = (z == 0) ? Wqb : (z == 1) ? Wkb : Xb;
    const int wr = (w >> 1) * 64, wc = (w & 1) * 64;

    f32x4 acc[4][4];
    #pragma unroll
    for (int i = 0; i < 4; ++i)
        #pragma unroll
        for (int j = 0; j < 4; ++j) acc[i][j] = (f32x4){0.f,0.f,0.f,0.f};

    for (int k0 = 0; k0 < DM; k0 += 32) {
        __syncthreads();
        #pragma unroll
        for (int p = 0; p < 2; ++p) {
            int ci = p * 256 + t;
            glds16(&aPtr[(size_t)(rowBase + (ci >> 2)) * DM + k0 + (ci & 3) * 8], &Ash[ci * 8]);
        }
        #pragma unroll
        for (int p = 0; p < 2; ++p) {
            int ci = p * 256 + t;
            glds16(&bPtr[(size_t)(colBase + (ci >> 2)) * DM + k0 + (ci & 3) * 8], &Bsh[ci * 8]);
        }
        __syncthreads();
        bf16x8 af[4], bfr[4];
        #pragma unroll
        for (int i = 0; i < 4; ++i) af[i]  = *(const bf16x8*)&Ash[(wr + i*16 + lcol)*32 + quad*8];
        #pragma unroll
        for (int i = 0; i < 4; ++i) bfr[i] = *(const bf16x8*)&Bsh[(wc + i*16 + lcol)*32 + quad*8];
        #pragma unroll
        for (int i = 0; i < 4; ++i)
            #pragma unroll
            for (int j = 0; j < 4; ++j)
                acc[i][j] = __builtin_amdgcn_mfma_f32_16x16x32_bf16(af[i], bfr[j], acc[i][j], 0, 0, 0);
    }

    unsigned short* Cm = (z == 0) ? Qo : (z == 1) ? Ko : Vto;
    const int ld = (z == 2) ? (S_ * 2) : DM;
    const float sc = (z == 0) ? QSCALE : 1.0f;
    #pragma unroll
    for (int i = 0; i < 4; ++i)
        #pragma unroll
        for (int j = 0; j < 4; ++j)
            #pragma unroll
            for (int r = 0; r < 4; ++r) {
                int row = rowBase + wr + i*16 + quad*4 + r;
                int col = colBase + wc + j*16 + lcol;
                Cm[(size_t)row * ld + col] = f2b(acc[i][j][r] * sc);
            }
}

// ---------------------------------------------------------------------------
// Flash attention, causal, S^T form, fixed softmax shift. 512 thr / 8 waves.
// Exact R2-measured kernel (45.0 us). Model (validated R2/R3/R6): time =
// (chunk-instances per CU = 34) x ~3.2k cyc, distribution-invariant -- so no
// split-k, no combine; the R6 split was pure overhead.
//   * waves = 4 q-groups(32 rows) x 2 k-halves(32): each K/V ds_read_b128
//     fragment feeds TWO 16-q MFMAs. One-time cross-wave o/l reduction at end.
//   * Ps LDS roundtrip eliminated: P -> PV-A-fragment via __shfl_xor(16) +
//     select; k-slot permutation sigma=[0,2,1,3] folded into V read offset.
// Causal bounds wave-uniform: k16 idx Kb = c*4 + kh*2 + nk, q16 idx
// Qb = tile*8 + wq*2 + qi, live iff Kb <= Qb, diagonal masked via mk[].
// Grid (32,16): bh = blockIdx.x pins bh to XCD; y<8 ? 15-y : y-8 keeps the
// complementary tile pairing.
// ---------------------------------------------------------------------------
__global__ __launch_bounds__(512, 4)
void attn_kernel(const unsigned short* __restrict__ Q,
                 const unsigned short* __restrict__ K,
                 const unsigned short* __restrict__ Vt,
                 unsigned short* __restrict__ Z)
{
    // [Kbuf0 | Kbuf1 | Vbuf0 | Vbuf1], each 64 rows x 72 shorts (16B row pad).
    // After the main loop the same 36,864B are reused as the f32 reduction
    // buffer (4 q-groups x 64 lanes x 36 f32, stride 144B -> 16B aligned).
    __shared__ __align__(16) unsigned short SH[18432];

    const int t = threadIdx.x;
    const int lane = t & 63, w = t >> 6;          // 8 waves
    const int lcol = lane & 15, quad = lane >> 4;
    const int kh = w & 1, wq = w >> 1;            // k-half (32), q-group (32)

    const int bh = blockIdx.x;                    // XCD = bh & 7
    const int b = bh >> 4, h = bh & 15;
    const int y = blockIdx.y;
    const int tile = (y < 8) ? (15 - y) : (y - 8);
    const int q0 = tile * 128;
    const int nchunk = 2 * tile + 2;              // k-chunks of 64

    const unsigned short* Qg = Q + (size_t)(b * S_ + q0) * DM + h * 64;
    const unsigned short* Kg = K + (size_t)(b * S_) * DM + h * 64;
    const unsigned short* Vg = Vt + (size_t)(h * 64) * (S_ * 2) + b * S_;

    // Q fragments: 2 q-subgroups of 16 x 2 hd-halves
    bf16x8 qf[2][2];
    #pragma unroll
    for (int qi = 0; qi < 2; ++qi)
        #pragma unroll
        for (int kd = 0; kd < 2; ++kd)
            qf[qi][kd] = *(const bf16x8*)&Qg[(size_t)(wq*32 + qi*16 + lcol) * DM + kd*32 + quad*8];

    // mask pattern inside the diagonal 16x16 block (S^T form: mask k > q)
    bool mk[4];
    #pragma unroll
    for (int r = 0; r < 4; ++r) mk[r] = (quad*4 + r) > lcol;

    float lp[2] = {0.f, 0.f};
    f32x4 o[2][4];
    #pragma unroll
    for (int qi = 0; qi < 2; ++qi)
        #pragma unroll
        for (int nd = 0; nd < 4; ++nd) o[qi][nd] = (f32x4){0.f,0.f,0.f,0.f};

    // staging: 64 rows x 8 16B-chunks per tile; one K + one V load per thread
    const int sr = t >> 3, sch = t & 7;

    // prologue: stage chunk 0 into buffer 0
    {
        uint4 k0 = *(const uint4*)&Kg[(size_t)sr * DM + sch * 8];
        uint4 v0 = *(const uint4*)&Vg[(size_t)sr * (S_ * 2) + sch * 8];
        *(uint4*)&SH[sr * 72 + sch * 8] = k0;
        *(uint4*)&SH[9216 + sr * 72 + sch * 8] = v0;
    }
    __syncthreads();

    const int Qb0 = tile * 8 + wq * 2;                  // q16 idx of qi=0
    const int gq = ((quad & 1) << 1) | (quad >> 1);     // sigma = [0,2,1,3]
    const bool qodd = (quad & 1) != 0;

    for (int c = 0; c < nchunk; ++c) {
        const int cur = c & 1;
        const bool pf = (c + 1 < nchunk);
        uint4 kn, vn;
        if (pf) {                                 // issue loads for chunk c+1
            const int kc1 = (c + 1) * 64;
            kn = *(const uint4*)&Kg[(size_t)(kc1 + sr) * DM + sch * 8];
            vn = *(const uint4*)&Vg[(size_t)sr * (S_ * 2) + kc1 + sch * 8];
        }
        const unsigned short* Kc = &SH[cur * 4608];
        const unsigned short* Vc = &SH[9216 + cur * 4608];

        const int Kb0 = c * 4 + kh * 2;           // k16 idx of nk=0
        if (Kb0 <= Qb0 + 1) {                     // at least (nk=0,qi=1) live
            uint32_t pw[2][2][2];                 // [qi][nk][word], bf16 pairs
            #pragma unroll
            for (int nk = 0; nk < 2; ++nk) {
                const int Kb = Kb0 + nk;
                if (Kb <= Qb0 + 1) {
                    bf16x8 ak0 = *(const bf16x8*)&Kc[(kh*32 + nk*16 + lcol)*72 + quad*8];
                    bf16x8 ak1 = *(const bf16x8*)&Kc[(kh*32 + nk*16 + lcol)*72 + 32 + quad*8];
                    #pragma unroll
                    for (int qi = 0; qi < 2; ++qi) {
                        if (Kb <= Qb0 + qi) {
                            f32x4 s = (f32x4){0.f,0.f,0.f,0.f};
                            s = __builtin_amdgcn_mfma_f32_16x16x32_bf16(ak0, qf[qi][0], s, 0, 0, 0);
                            s = __builtin_amdgcn_mfma_f32_16x16x32_bf16(ak1, qf[qi][1], s, 0, 0, 0);
                            float p0 = __builtin_amdgcn_exp2f(s[0]);
                            float p1 = __builtin_amdgcn_exp2f(s[1]);
                            float p2 = __builtin_amdgcn_exp2f(s[2]);
                            float p3 = __builtin_amdgcn_exp2f(s[3]);
                            if (Kb == Qb0 + qi) { // diagonal block, uniform
                                p0 = mk[0] ? 0.f : p0;
                                p1 = mk[1] ? 0.f : p1;
                                p2 = mk[2] ? 0.f : p2;
                                p3 = mk[3] ? 0.f : p3;
                            }
                            lp[qi] += (p0 + p1) + (p2 + p3);
                            pw[qi][nk][0] = pack2bf(p0, p1);
                            pw[qi][nk][1] = pack2bf(p2, p3);
                        } else {
                            pw[qi][nk][0] = 0u;
                            pw[qi][nk][1] = 0u;
                        }
                    }
                } else {
                    #pragma unroll
                    for (int qi = 0; qi < 2; ++qi) {
                        pw[qi][nk][0] = 0u;
                        pw[qi][nk][1] = 0u;
                    }
                }
            }

            // register->A-fragment transform via shfl_xor(16) + select.
            // Source: lane (quad,q) word layout  a0={4q,4q+1} a1={4q+2,4q+3}
            //         b0={16+4q,16+4q+1} b1={16+4q+2,16+4q+3}
            // Dest quad d holds k-group sigma(d)*8..+7 ascending, sigma=[0,2,1,3];
            // V reads apply the same sigma via gq.
            bf16x8 ap[2];
            #pragma unroll
            for (int qi = 0; qi < 2; ++qi) {
                uint32_t a0 = pw[qi][0][0], a1 = pw[qi][0][1];
                uint32_t b0 = pw[qi][1][0], b1 = pw[qi][1][1];
                uint32_t xa0 = (uint32_t)__shfl_xor((int)a0, 16);
                uint32_t xa1 = (uint32_t)__shfl_xor((int)a1, 16);
                uint32_t xb0 = (uint32_t)__shfl_xor((int)b0, 16);
                uint32_t xb1 = (uint32_t)__shfl_xor((int)b1, 16);
                u32x4 apw;
                apw[0] = qodd ? xb0 : a0;
                apw[1] = qodd ? xb1 : a1;
                apw[2] = qodd ? b0 : xa0;
                apw[3] = qodd ? b1 : xa1;
                ap[qi] = __builtin_bit_cast(bf16x8, apw);
            }

            #pragma unroll
            for (int nd = 0; nd < 4; ++nd) {
                bf16x8 bv = *(const bf16x8*)&Vc[(nd*16 + lcol)*72 + kh*32 + gq*8];
                #pragma unroll
                for (int qi = 0; qi < 2; ++qi)
                    o[qi][nd] = __builtin_amdgcn_mfma_f32_16x16x32_bf16(ap[qi], bv, o[qi][nd], 0, 0, 0);
            }
        }

        if (pf) {                                 // write chunk c+1 into buf^1
            *(uint4*)&SH[(cur ^ 1) * 4608 + sr * 72 + sch * 8] = kn;
            *(uint4*)&SH[9216 + (cur ^ 1) * 4608 + sr * 72 + sch * 8] = vn;
        }
        __syncthreads();   // readers of buf^1 (iter c-1) done before its write
                           // is visible-required; writers done before iter c+1
    }

    // ---- combine k-halves: partner waves (wq,kh=1) -> (wq,kh=0) via LDS ----
    #pragma unroll
    for (int qi = 0; qi < 2; ++qi) {
        lp[qi] += __shfl_xor(lp[qi], 16);
        lp[qi] += __shfl_xor(lp[qi], 32);
    }
    float* red = (float*)SH;
    float* my = red + (wq * 64 + lane) * 36;      // 144B stride: 16B aligned
    if (kh == 1) {
        #pragma unroll
        for (int qi = 0; qi < 2; ++qi)
            #pragma unroll
            for (int nd = 0; nd < 4; ++nd)
                *(f32x4*)&my[qi*16 + nd*4] = o[qi][nd];
        my[32] = lp[0];
        my[33] = lp[1];
    }
    __syncthreads();
    if (kh == 0) {
        #pragma unroll
        for (int qi = 0; qi < 2; ++qi)
            #pragma unroll
            for (int nd = 0; nd < 4; ++nd)
                o[qi][nd] += *(const f32x4*)&my[qi*16 + nd*4];
        float linv[2];
        linv[0] = 1.0f / (lp[0] + my[32]);
        linv[1] = 1.0f / (lp[1] + my[33]);
        #pragma unroll
        for (int qi = 0; qi < 2; ++qi)
            #pragma unroll
            for (int r = 0; r < 4; ++r) {
                float lr = __shfl(linv[qi], quad*4 + r);
                unsigned short* Zr = Z + (size_t)(b*S_ + q0 + wq*32 + qi*16 + quad*4 + r) * DM + h*64;
                #pragma unroll
                for (int nd = 0; nd < 4; ++nd)
                    Zr[nd*16 + lcol] = f2b(o[qi][nd][r] * lr);
            }
    }
}

// ---------------------------------------------------------------------------
// Output projection, R15: tile 128x128 (m97 shape, 16 MFMA : 8 ds_read per
// wave-step vs the old 64x128's 8 : 6), grid (32,8) = 256 blocks, 256 thr /
// 4 waves, wave sub-tile 64x64. Both operands bf16 via glds.
// out = Zb @ Wob^T + bo, fp32.
// ---------------------------------------------------------------------------
__global__ __launch_bounds__(256, 2)
void out_gemm(const unsigned short* __restrict__ A,
              const unsigned short* __restrict__ Wob, const float* __restrict__ bo,
              float* __restrict__ Out)
{
    __shared__ unsigned short Ash[128 * 32];
    __shared__ unsigned short Bsh[128 * 32];

    const int t = threadIdx.x;
    const int lane = t & 63, w = t >> 6;          // 4 waves
    const int lcol = lane & 15, quad = lane >> 4;
    const int rowBase = blockIdx.x * 128;         // token panel (32)
    const int colBase = blockIdx.y * 128;         // feature panel (8)
    const int wr = (w >> 1) * 64, wc = (w & 1) * 64;

    f32x4 acc[4][4];
    #pragma unroll
    for (int i = 0; i < 4; ++i)
        #pragma unroll
        for (int j = 0; j < 4; ++j) acc[i][j] = (f32x4){0.f,0.f,0.f,0.f};

    for (int k0 = 0; k0 < DM; k0 += 32) {
        __syncthreads();
        #pragma unroll
        for (int p = 0; p < 2; ++p) {
            int ci = p * 256 + t;
            glds16(&A[(size_t)(rowBase + (ci >> 2)) * DM + k0 + (ci & 3) * 8], &Ash[ci * 8]);
        }
        #pragma unroll
        for (int p = 0; p < 2; ++p) {
            int ci = p * 256 + t;
            glds16(&Wob[(size_t)(colBase + (ci >> 2)) * DM + k0 + (ci & 3) * 8], &Bsh[ci * 8]);
        }
        __syncthreads();
        bf16x8 af[4], bfr[4];
        #pragma unroll
        for (int i = 0; i < 4; ++i) af[i]  = *(const bf16x8*)&Ash[(wr + i*16 + lcol)*32 + quad*8];
        #pragma unroll
        for (int j = 0; j < 4; ++j) bfr[j] = *(const bf16x8*)&Bsh[(wc + j*16 + lcol)*32 + quad*8];
        #pragma unroll
        for (int i = 0; i < 4; ++i)
            #pragma unroll
            for (int j = 0; j < 4; ++j)
                acc[i][j] = __builtin_amdgcn_mfma_f32_16x16x32_bf16(af[i], bfr[j], acc[i][j], 0, 0, 0);
    }

    float bb[4];
    #pragma unroll
    for (int j = 0; j < 4; ++j) bb[j] = bo[colBase + wc + j*16 + lcol];

    #pragma unroll
    for (int i = 0; i < 4; ++i)
        #pragma unroll
        for (int j = 0; j < 4; ++j)
            #pragma unroll
            for (int r = 0; r < 4; ++r) {
                int row = rowBase + wr + i*16 + quad*4 + r;
                int col = colBase + wc + j*16 + lcol;
                Out[(size_t)row * DM + col] = acc[i][j][r] + bb[j];
            }
}

// ---------------------------------------------------------------------------
extern "C" void kernel_launch(void* const* d_in, const int* in_sizes, int n_in,
                              void* d_out, int out_size, void* d_ws, size_t ws_size,
                              hipStream_t stream) {
    const float* X  = (const float*)d_in[0];
    const float* Wq = (const float*)d_in[1];
    const float* Wk = (const float*)d_in[2];
    const float* Wv = (const float*)d_in[3];
    const float* Wo = (const float*)d_in[4];
    const float* bo = (const float*)d_in[5];
    float* out = (float*)d_out;

    // ws (32 MB): [Xb/Zb 8MB][Qw/Wob 8MB][Kw 8MB][Vtw 8MB]
    unsigned short* Xb  = (unsigned short*)d_ws;
    unsigned short* Qw  = Xb + (size_t)4096 * 1024;
    unsigned short* Kw  = Qw + (size_t)4096 * 1024;
    unsigned short* Vtw = Kw + (size_t)4096 * 1024;
    unsigned short* Zb  = Xb;                      // Xb dead after qkv_gemm
    unsigned short* Wob = Qw;                      // Qw dead after attn_kernel
    // bf16 qkv-weights staged in d_out (6 MB of 16 MB); consumed by qkv_gemm,
    // which completes before out_gemm overwrites d_out (stream-ordered).
    unsigned short* Wb  = (unsigned short*)d_out;

    cvt_all<<<dim3(7168), 256, 0, stream>>>(X, Wq, Wk, Wv, Xb, Wb);
    qkv_gemm<<<dim3(32, 8, 3), 256, 0, stream>>>(Xb, Wb, Wb + (size_t)1048576,
                                                 Wb + (size_t)2097152, Qw, Kw, Vtw);
    attn_kernel<<<dim3(32, 16), 512, 0, stream>>>(Qw, Kw, Vtw, Zb);
    cvt_wo<<<dim3(1024), 256, 0, stream>>>(Wo, Wob);
    out_gemm<<<dim3(32, 8), 256, 0, stream>>>(Zb, Wob, bo, out);
}